// Round 1
// baseline (1643.980 us; speedup 1.0000x reference)
//
#include <hip/hip_runtime.h>
#include <cstdint>
#include <cstddef>

// Problem constants (from reference): E experts, N tokens/expert, D dim, H hidden
#define NE 16
#define NTOK 2048
#define DDIM 1024
#define HDIM 4096

typedef unsigned short u16;
typedef __bf16 bf16x8 __attribute__((ext_vector_type(8)));
typedef float f32x4 __attribute__((ext_vector_type(4)));

typedef __attribute__((address_space(1))) const void as1_cvoid;
typedef __attribute__((address_space(3))) void as3_void;

// async global->LDS, 16B per lane. LDS dest must be wave-uniform base; HW
// scatters lane i to base + i*16.
__device__ __forceinline__ void load_lds16(const void* g, void* l) {
    __builtin_amdgcn_global_load_lds((as1_cvoid*)g, (as3_void*)l, 16, 0, 0);
}

// fp32 -> bf16 round-to-nearest-even
__device__ __forceinline__ u16 f2bf(float f) {
    uint32_t x = __float_as_uint(f);
    x += 0x7FFFu + ((x >> 16) & 1u);
    return (u16)(x >> 16);
}

// ---- elementwise cast x: fp32 -> bf16, 4 elems/thread ----
__global__ void cvt_x_kernel(const float* __restrict__ in, u16* __restrict__ out, size_t n4) {
    size_t i = (size_t)blockIdx.x * blockDim.x + threadIdx.x;
    if (i >= n4) return;
    float4 v = ((const float4*)in)[i];
    uint32_t lo = (uint32_t)f2bf(v.x) | ((uint32_t)f2bf(v.y) << 16);
    uint32_t hi = (uint32_t)f2bf(v.z) | ((uint32_t)f2bf(v.w) << 16);
    ((uint2*)out)[i] = make_uint2(lo, hi);
}

// ---- per-expert transpose + cast: in [E][R][C] fp32 -> out [E][C][R] bf16 ----
__global__ void transpose_cvt_kernel(const float* __restrict__ in, u16* __restrict__ out,
                                     int R, int C) {
    __shared__ u16 tile[32][33];
    int e = blockIdx.z;
    const float* pin = in + (size_t)e * R * C;
    u16* pout = out + (size_t)e * R * C;
    int c0 = blockIdx.x * 32, r0 = blockIdx.y * 32;
#pragma unroll
    for (int i = 0; i < 4; ++i) {
        int r = r0 + threadIdx.y + i * 8;
        tile[threadIdx.y + i * 8][threadIdx.x] = f2bf(pin[(size_t)r * C + c0 + threadIdx.x]);
    }
    __syncthreads();
#pragma unroll
    for (int i = 0; i < 4; ++i) {
        int c = c0 + threadIdx.y + i * 8;
        pout[(size_t)c * R + r0 + threadIdx.x] = tile[threadIdx.x][threadIdx.y + i * 8];
    }
}

// ---- m97-style bf16 GEMM: C[e] = A[e] (MxK) * Bt[e]^T (Bt is [Nout][K]) ----
// 128x128 tile per 256-thread block (4 waves, 2x2 of 64x64), BK=64,
// global_load_lds width-16 staging, 16x16x32 bf16 MFMA, 4x4 acc per wave.
// GELU_BF16: epilogue adds bias, applies exact gelu, stores bf16.
// else:      epilogue adds bias, stores fp32.
template <bool GELU_BF16>
__global__ void __launch_bounds__(256)
gemm_bt_kernel(const u16* __restrict__ A, const u16* __restrict__ Bt,
               const float* __restrict__ bias, void* __restrict__ Cout,
               int M, int K, int Nout) {
    __shared__ u16 As[128 * 64];  // 16 KB
    __shared__ u16 Bs[128 * 64];  // 16 KB

    const int e = blockIdx.z;
    const u16* Ae = A + (size_t)e * M * K;
    const u16* Be = Bt + (size_t)e * Nout * K;

    const int t = threadIdx.x;
    const int wave = t >> 6;
    const int lane = t & 63;

    const int m_blk = blockIdx.y * 128;
    const int n_blk = blockIdx.x * 128;
    const int wm = (wave >> 1) * 64;
    const int wn = (wave & 1) * 64;

    // staging: load l = wave*4+i covers rows l*8 .. l*8+7 of the 128-row tile;
    // lane -> (row = lane>>3, 16B chunk = lane&7). LDS lands contiguous.
    const int ld_row = wave * 32 + (lane >> 3);
    const int ld_col = (lane & 7) * 8;
    const u16* a_g = Ae + (size_t)(m_blk + ld_row) * K + ld_col;
    const u16* b_g = Be + (size_t)(n_blk + ld_row) * K + ld_col;
    u16* a_l = As + wave * 4 * 512;  // 512 u16 = 1024 B per wave-load
    u16* b_l = Bs + wave * 4 * 512;

    f32x4 acc[4][4];
#pragma unroll
    for (int i = 0; i < 4; ++i)
#pragma unroll
        for (int j = 0; j < 4; ++j)
            acc[i][j] = (f32x4){0.f, 0.f, 0.f, 0.f};

    const int frag_row_a = wm + (lane & 15);
    const int frag_row_b = wn + (lane & 15);
    const int frag_k = (lane >> 4) * 8;

    for (int k0 = 0; k0 < K; k0 += 64) {
        __syncthreads();  // previous compute done before LDS overwrite
#pragma unroll
        for (int i = 0; i < 4; ++i) {
            load_lds16(a_g + (size_t)i * 8 * K + k0, a_l + i * 512);
            load_lds16(b_g + (size_t)i * 8 * K + k0, b_l + i * 512);
        }
        __syncthreads();  // staging complete
#pragma unroll
        for (int ks = 0; ks < 2; ++ks) {
            bf16x8 af[4], bf[4];
#pragma unroll
            for (int i = 0; i < 4; ++i)
                af[i] = *(const bf16x8*)&As[(frag_row_a + i * 16) * 64 + ks * 32 + frag_k];
#pragma unroll
            for (int j = 0; j < 4; ++j)
                bf[j] = *(const bf16x8*)&Bs[(frag_row_b + j * 16) * 64 + ks * 32 + frag_k];
#pragma unroll
            for (int i = 0; i < 4; ++i)
#pragma unroll
                for (int j = 0; j < 4; ++j)
                    acc[i][j] = __builtin_amdgcn_mfma_f32_16x16x32_bf16(af[i], bf[j], acc[i][j], 0, 0, 0);
        }
    }

    // epilogue: C/D layout col = lane&15, row = (lane>>4)*4 + r  [m89/m91]
    const int rbase = (lane >> 4) * 4;
    const int cbase = lane & 15;
#pragma unroll
    for (int i = 0; i < 4; ++i) {
#pragma unroll
        for (int j = 0; j < 4; ++j) {
            const int col = n_blk + wn + j * 16 + cbase;
            const float bv = bias[col];
#pragma unroll
            for (int r = 0; r < 4; ++r) {
                const int row = m_blk + wm + i * 16 + rbase + r;
                float v = acc[i][j][r] + bv;
                if (GELU_BF16) {
                    float g = 0.5f * v * (1.0f + erff(v * 0.70710678118654752f));
                    ((u16*)Cout)[(size_t)e * M * Nout + (size_t)row * Nout + col] = f2bf(g);
                } else {
                    ((float*)Cout)[(size_t)e * M * Nout + (size_t)row * Nout + col] = v;
                }
            }
        }
    }
}

extern "C" void kernel_launch(void* const* d_in, const int* in_sizes, int n_in,
                              void* d_out, int out_size, void* d_ws, size_t ws_size,
                              hipStream_t stream) {
    (void)in_sizes; (void)n_in; (void)out_size; (void)ws_size;
    const float* x  = (const float*)d_in[0];
    const float* w1 = (const float*)d_in[1];
    const float* w2 = (const float*)d_in[2];
    const float* b1 = (const float*)d_in[3];
    const float* b2 = (const float*)d_in[4];
    float* out = (float*)d_out;

    // workspace layout (bytes):
    //   xb  : E*N*D*2  =  64 MiB   (x in bf16)
    //   w1t : E*H*D*2  = 128 MiB   (w1^T per expert, bf16, [e][h][d])
    //   w2t : E*D*H*2  = 128 MiB   (w2^T per expert, bf16, [e][d][h])
    //   hid : E*N*H*2  = 256 MiB   (gelu(x@w1+b1) in bf16)
    char* ws = (char*)d_ws;
    u16* xb  = (u16*)ws;
    u16* w1t = (u16*)(ws + (size_t)NE * NTOK * DDIM * 2);
    u16* w2t = (u16*)(ws + (size_t)NE * NTOK * DDIM * 2 + (size_t)NE * HDIM * DDIM * 2);
    u16* hid = (u16*)(ws + (size_t)NE * NTOK * DDIM * 2 + (size_t)2 * NE * HDIM * DDIM * 2);

    // 1) casts / transposes
    {
        size_t n4 = (size_t)NE * NTOK * DDIM / 4;
        cvt_x_kernel<<<(unsigned)((n4 + 255) / 256), 256, 0, stream>>>(x, xb, n4);
    }
    transpose_cvt_kernel<<<dim3(HDIM / 32, DDIM / 32, NE), dim3(32, 8), 0, stream>>>(w1, w1t, DDIM, HDIM);
    transpose_cvt_kernel<<<dim3(DDIM / 32, HDIM / 32, NE), dim3(32, 8), 0, stream>>>(w2, w2t, HDIM, DDIM);

    // 2) hidden = gelu(x @ w1 + b1), bf16 out
    gemm_bt_kernel<true><<<dim3(HDIM / 128, NTOK / 128, NE), 256, 0, stream>>>(
        xb, w1t, b1, (void*)hid, NTOK, DDIM, HDIM);

    // 3) out = hidden @ w2 + b2, fp32 out
    gemm_bt_kernel<false><<<dim3(DDIM / 128, NTOK / 128, NE), 256, 0, stream>>>(
        hid, w2t, b2, (void*)out, NTOK, HDIM, DDIM);
}